// Round 6
// baseline (812.501 us; speedup 1.0000x reference)
//
#include <hip/hip_runtime.h>

#define NN 20000
#define DD 128
#define HH 128
#define G4 512
#define DEG 32
#define NPB 32     // nodes per pair (2 staggered groups of 16)
#define PAIRS 625  // NN/NPB; grid = 625, 3 blocks/CU on 113 CUs (VGPR<=85 -> 2016<=2048)

typedef __attribute__((ext_vector_type(4))) float f32x4;
typedef __attribute__((ext_vector_type(8))) short s16x8;

#ifndef __has_builtin
#define __has_builtin(x) 0
#endif

static __device__ __forceinline__ float fexp2(float x){
#if __has_builtin(__builtin_amdgcn_exp2f)
  return __builtin_amdgcn_exp2f(x);
#else
  return exp2f(x);
#endif
}
static __device__ __forceinline__ float frcp(float x){
#if __has_builtin(__builtin_amdgcn_rcpf)
  return __builtin_amdgcn_rcpf(x);
#else
  return 1.f/x;
#endif
}

// packed f32x2 -> bf16x2 (RNE)
static __device__ __forceinline__ unsigned cvt_pk_bf16(float lo, float hi){
  unsigned r;
  asm("v_cvt_pk_bf16_f32 %0, %1, %2" : "=v"(r) : "v"(lo), "v"(hi));
  return r;
}
static __device__ __forceinline__ s16x8 ld8bf(const float* __restrict__ p){
  f32x4 a = *(const f32x4*)p;
  f32x4 b = *(const f32x4*)(p+4);
  union{unsigned u[4]; s16x8 v;} z;
  z.u[0]=cvt_pk_bf16(a[0],a[1]);
  z.u[1]=cvt_pk_bf16(a[2],a[3]);
  z.u[2]=cvt_pk_bf16(b[0],b[1]);
  z.u[3]=cvt_pk_bf16(b[2],b[3]);
  return z.v;
}
// bf16 packed in u32 -> f32 (bf16 in high 16 bits IS the f32 bit pattern)
static __device__ __forceinline__ float lo16f(unsigned u){
  union{unsigned x; float f;} v; v.x = u << 16; return v.f;
}
static __device__ __forceinline__ float hi16f(unsigned u){
  union{unsigned x; float f;} v; v.x = u & 0xffff0000u; return v.f;
}
#define NLOG2E -1.44269504f
#define TLOG2E  2.88539008f

// ---------------- Phase 1: Hp = h @ W_ih^T + b_ih + b_hh, bf16 ----------------
// PERMUTED layout: Hp element (n, gatecol=128g+16w+4hi+r) stored at
//   n*512 + w*64 + hi*16 + g*4 + r
// so in k_lstm each lane's 16 gate-values are one contiguous 32B chunk
// (2x dwordx4 gather loads; 4 hi-lanes cover a full 128B line).
__global__ __launch_bounds__(512,2) void k_hp(
    const float* __restrict__ h, const float* __restrict__ W_ih,
    const float* __restrict__ b_ih, const float* __restrict__ b_hh,
    unsigned short* __restrict__ Hp)
{
  const int tid=threadIdx.x, w=tid>>6, lane=tid&63, lo=lane&15, hi=lane>>4;
  s16x8 A[4][4];
#pragma unroll
  for(int g=0;g<4;++g){
    const float* wr=W_ih+(size_t)(128*g+16*w+lo)*DD+8*hi;
#pragma unroll
    for(int c=0;c<4;++c) A[g][c]=ld8bf(wr+32*c);
  }
  f32x4 bb[4];
#pragma unroll
  for(int g=0;g<4;++g){
    const int gcb=128*g+16*w+4*hi;
    bb[g]=*(const f32x4*)(b_ih+gcb) + *(const f32x4*)(b_hh+gcb);
  }
  // grid 256, blocks 0..56 take a second 64-node chunk (313 chunks total)
  const int nchunk = (blockIdx.x < 57) ? 2 : 1;
  for(int cc=0; cc<nchunk; ++cc){
    const int n0 = ((cc? 256+blockIdx.x : blockIdx.x))*64;
    f32x4 acc[4][4];
#pragma unroll
    for(int g=0;g<4;++g)
#pragma unroll
      for(int nt=0;nt<4;++nt) acc[g][nt]=(f32x4)0.f;
#pragma unroll
    for(int c=0;c<4;++c){
      s16x8 B[4];
#pragma unroll
      for(int nt=0;nt<4;++nt){
        int nd=n0+16*nt+lo; if(nd>=NN) nd=NN-1;
        B[nt]=ld8bf(h+(size_t)nd*DD+32*c+8*hi);
      }
#pragma unroll
      for(int g=0;g<4;++g)
#pragma unroll
        for(int nt=0;nt<4;++nt)
          acc[g][nt]=__builtin_amdgcn_mfma_f32_16x16x32_bf16(A[g][c],B[nt],acc[g][nt],0,0,0);
    }
#pragma unroll
    for(int nt=0;nt<4;++nt){
      int nd=n0+16*nt+lo;
      if(nd<NN){
        unsigned short* p = Hp + (size_t)nd*G4 + w*64 + hi*16;
        uint4 q0, q1;
        q0.x=cvt_pk_bf16(acc[0][nt][0]+bb[0][0], acc[0][nt][1]+bb[0][1]);
        q0.y=cvt_pk_bf16(acc[0][nt][2]+bb[0][2], acc[0][nt][3]+bb[0][3]);
        q0.z=cvt_pk_bf16(acc[1][nt][0]+bb[1][0], acc[1][nt][1]+bb[1][1]);
        q0.w=cvt_pk_bf16(acc[1][nt][2]+bb[1][2], acc[1][nt][3]+bb[1][3]);
        q1.x=cvt_pk_bf16(acc[2][nt][0]+bb[2][0], acc[2][nt][1]+bb[2][1]);
        q1.y=cvt_pk_bf16(acc[2][nt][2]+bb[2][2], acc[2][nt][3]+bb[2][3]);
        q1.z=cvt_pk_bf16(acc[3][nt][0]+bb[3][0], acc[3][nt][1]+bb[3][1]);
        q1.w=cvt_pk_bf16(acc[3][nt][2]+bb[3][2], acc[3][nt][3]+bb[3][3]);
        *(uint4*)p = q0;
        *(uint4*)(p+8) = q1;
      }
    }
  }
}

// unpack one lane's 32B Hp chunk into the 4-gate accumulator init
static __device__ __forceinline__ void unpack_acc(const uint4 q[2], f32x4 acc[4]){
  acc[0][0]=lo16f(q[0].x); acc[0][1]=hi16f(q[0].x); acc[0][2]=lo16f(q[0].y); acc[0][3]=hi16f(q[0].y);
  acc[1][0]=lo16f(q[0].z); acc[1][1]=hi16f(q[0].z); acc[1][2]=lo16f(q[0].w); acc[1][3]=hi16f(q[0].w);
  acc[2][0]=lo16f(q[1].x); acc[2][1]=hi16f(q[1].x); acc[2][2]=lo16f(q[1].y); acc[2][3]=hi16f(q[1].y);
  acc[3][0]=lo16f(q[1].z); acc[3][1]=hi16f(q[1].z); acc[3][2]=lo16f(q[1].w); acc[3][3]=hi16f(q[1].w);
}

// ---------------- Phase 2: LSTM scan, staggered pipeline, 3-blocks/CU single epoch -----
// Grid = 625, one pair per block. amdgpu_waves_per_eu(6) caps VGPR at 512/6 -> 84-85,
// which this body already fits (round-5 measured 84), so NO spills, and the CP can pack
// 3 blocks/CU (3*8*84 = 2016 <= 2048 VGPR, 38.4 KB LDS) -> all 625 pairs co-resident,
// wall ~= one pair-time instead of two.  (launch_bounds' 2nd arg is min BLOCKS/CU and
// over-caps: (512,6) -> VGPR 40 spill disaster in round 4.)
__global__ __launch_bounds__(512) __attribute__((amdgpu_waves_per_eu(6))) void k_lstm(
    const float* __restrict__ h, const int* __restrict__ nbr,
    const float* __restrict__ W_hh, const unsigned short* __restrict__ Hp,
    const float* __restrict__ W_out, const float* __restrict__ b_out,
    float* __restrict__ out)
{
  __shared__ unsigned short hpA[16*HH];      // 4 KB
  __shared__ unsigned short hpB[16*HH];      // 4 KB
  __shared__ int nlds[DEG*NPB];              // transposed: nlds[t][node] = node_idx*G4, 4 KB
  const int tid=threadIdx.x, w=tid>>6, lane=tid&63, lo=lane&15, hi=lane>>4;
  const int n0=blockIdx.x*NPB;
  const int swz=(lo&7)<<4;
  const int woff=w*64+hi*16;                 // lane's Hp chunk offset (shorts)

  s16x8 A[4][4];                             // W_hh fragments in registers (64 VGPR)
#pragma unroll
  for(int g=0;g<4;++g){
    const float* wr=W_hh+(size_t)(128*g+16*w+lo)*HH+8*hi;
#pragma unroll
    for(int c=0;c<4;++c) A[g][c]=ld8bf(wr+32*c);
  }
  {
    unsigned* za=(unsigned*)&hpA[0];
    unsigned* zb=(unsigned*)&hpB[0];
    za[tid]=0u; za[tid+512]=0u;              // zero hpA (h0 = 0)
    zb[tid]=0u; zb[tid+512]=0u;              // zero hpB
#pragma unroll
    for(int i=0;i<2;++i){                    // stage neighbor offsets transposed, pre-scaled
      int idx=tid+512*i;
      nlds[(idx&31)*NPB + (idx>>5)] = nbr[n0*DEG + idx]*G4;
    }
  }
  __syncthreads();

  float cstA[4]={0.f,0.f,0.f,0.f}, cstB[4]={0.f,0.f,0.f,0.f};
  // accB(-1)=0 makes the first cellB produce h=0, c=0: exactly h_B(-1).
  f32x4 accB[4];
#pragma unroll
  for(int g=0;g<4;++g) accB[g]=(f32x4)0.f;

  // depth-1 gather prologue: step 0 for both groups (2 intervals of slack per gather)
  uint4 qA0[2], qB0[2];
  {
    const unsigned short* ga=Hp+(size_t)nlds[lo]+woff;
    const unsigned short* gb=Hp+(size_t)nlds[16+lo]+woff;
    qA0[0]=*(const uint4*)ga; qA0[1]=*(const uint4*)(ga+8);
    qB0[0]=*(const uint4*)gb; qB0[1]=*(const uint4*)(gb+8);
  }

  for(int t=0;t<DEG;++t){
    const int tn = (t+1<DEG)? t+1 : t;
    // ================= interval P: MFMA group A  ||  cell group B =================
    uint4 qA1[2];
    {
      const unsigned short* gp=Hp+(size_t)nlds[tn*NPB+lo]+woff;
      qA1[0]=*(const uint4*)gp; qA1[1]=*(const uint4*)(gp+8);
    }
    // B fragments for group A from hpA (swizzled ds_read_b128)
    s16x8 Ba[4];
    const char* ra=(const char*)&hpA[0];
#pragma unroll
    for(int c=0;c<4;++c)
      Ba[c]=*(const s16x8*)(ra + ((lo*256 + 64*c + 16*hi) ^ swz));
    // cell update for group B (consumes accB from previous interval) -> write hpB
    {
      float hv[4];
#pragma unroll
      for(int r=0;r<4;++r){
        float ei=fexp2(accB[0][r]*NLOG2E);
        float ef=fexp2(accB[1][r]*NLOG2E);
        float eg=fexp2(accB[2][r]*TLOG2E);
        float eo=fexp2(accB[3][r]*NLOG2E);
        float itg=(eg-1.f)*frcp((1.f+ei)*(1.f+eg));
        float cc=cstB[r]*frcp(1.f+ef)+itg;
        cstB[r]=cc;
        float ec=fexp2(cc*TLOG2E);
        hv[r]=(ec-1.f)*frcp((1.f+eo)*(1.f+ec));
      }
      uint2 pk;
      pk.x=cvt_pk_bf16(hv[0],hv[1]);
      pk.y=cvt_pk_bf16(hv[2],hv[3]);
      char* wb=(char*)&hpB[0];
      *(uint2*)(wb + ((lo*256 + 32*w + 8*hi) ^ swz)) = pk;
    }
    // acc init from step-t gather + MFMA for group A
    f32x4 accA[4];
    unpack_acc(qA0, accA);
#pragma unroll
    for(int c=0;c<4;++c)
#pragma unroll
      for(int g=0;g<4;++g)
        accA[g]=__builtin_amdgcn_mfma_f32_16x16x32_bf16(A[g][c],Ba[c],accA[g],0,0,0);
    qA0[0]=qA1[0]; qA0[1]=qA1[1];
    asm volatile("s_waitcnt lgkmcnt(0)\n\ts_barrier" ::: "memory");

    // ================= interval Q: MFMA group B  ||  cell group A =================
    uint4 qB1[2];
    {
      const unsigned short* gp=Hp+(size_t)nlds[tn*NPB+16+lo]+woff;
      qB1[0]=*(const uint4*)gp; qB1[1]=*(const uint4*)(gp+8);
    }
    s16x8 Bb[4];
    const char* rb=(const char*)&hpB[0];
#pragma unroll
    for(int c=0;c<4;++c)
      Bb[c]=*(const s16x8*)(rb + ((lo*256 + 64*c + 16*hi) ^ swz));
    // cell update for group A (consumes accA) -> write hpA
    {
      float hv[4];
#pragma unroll
      for(int r=0;r<4;++r){
        float ei=fexp2(accA[0][r]*NLOG2E);
        float ef=fexp2(accA[1][r]*NLOG2E);
        float eg=fexp2(accA[2][r]*TLOG2E);
        float eo=fexp2(accA[3][r]*NLOG2E);
        float itg=(eg-1.f)*frcp((1.f+ei)*(1.f+eg));
        float cc=cstA[r]*frcp(1.f+ef)+itg;
        cstA[r]=cc;
        float ec=fexp2(cc*TLOG2E);
        hv[r]=(ec-1.f)*frcp((1.f+eo)*(1.f+ec));
      }
      uint2 pk;
      pk.x=cvt_pk_bf16(hv[0],hv[1]);
      pk.y=cvt_pk_bf16(hv[2],hv[3]);
      char* wb=(char*)&hpA[0];
      *(uint2*)(wb + ((lo*256 + 32*w + 8*hi) ^ swz)) = pk;
    }
    // acc init + MFMA for group B
    unpack_acc(qB0, accB);
#pragma unroll
    for(int c=0;c<4;++c)
#pragma unroll
      for(int g=0;g<4;++g)
        accB[g]=__builtin_amdgcn_mfma_f32_16x16x32_bf16(A[g][c],Bb[c],accB[g],0,0,0);
    qB0[0]=qB1[0]; qB0[1]=qB1[1];
    asm volatile("s_waitcnt lgkmcnt(0)\n\ts_barrier" ::: "memory");
  }

  // drain: cell for group B at t=31 -> hpB holds h_B(31)
  {
    float hv[4];
#pragma unroll
    for(int r=0;r<4;++r){
      float ei=fexp2(accB[0][r]*NLOG2E);
      float ef=fexp2(accB[1][r]*NLOG2E);
      float eg=fexp2(accB[2][r]*TLOG2E);
      float eo=fexp2(accB[3][r]*NLOG2E);
      float itg=(eg-1.f)*frcp((1.f+ei)*(1.f+eg));
      float cc=cstB[r]*frcp(1.f+ef)+itg;
      float ec=fexp2(cc*TLOG2E);
      hv[r]=(ec-1.f)*frcp((1.f+eo)*(1.f+ec));
    }
    uint2 pk;
    pk.x=cvt_pk_bf16(hv[0],hv[1]);
    pk.y=cvt_pk_bf16(hv[2],hv[3]);
    char* wb=(char*)&hpB[0];
    *(uint2*)(wb + ((lo*256 + 32*w + 8*hi) ^ swz)) = pk;
  }
  asm volatile("s_waitcnt lgkmcnt(0)\n\ts_barrier" ::: "memory");

  // ---- fused output projection: out = relu([h, agg] @ W_out^T + b_out) ----
  s16x8 AO[8];
  {
    const float* wr=W_out+(size_t)(16*w+lo)*256+8*hi;
#pragma unroll
    for(int c=0;c<8;++c) AO[c]=ld8bf(wr+32*c);
  }
  const int ob=16*w+4*hi;
  f32x4 bias=*(const f32x4*)(b_out+ob);
#pragma unroll
  for(int nt=0;nt<2;++nt){
    const int node=n0+nt*16+lo;
    s16x8 BB[8];
    const float* hr=h+(size_t)node*DD+8*hi;
#pragma unroll
    for(int c=0;c<4;++c) BB[c]=ld8bf(hr+32*c);
    const char* rb=(const char*)(nt? &hpB[0] : &hpA[0]);
#pragma unroll
    for(int c=0;c<4;++c)
      BB[4+c]=*(const s16x8*)(rb + ((lo*256 + 64*c + 16*hi) ^ swz));
    f32x4 acc=(f32x4)0.f;
#pragma unroll
    for(int c=0;c<8;++c) acc=__builtin_amdgcn_mfma_f32_16x16x32_bf16(AO[c],BB[c],acc,0,0,0);
#pragma unroll
    for(int r=0;r<4;++r){ float v=acc[r]+bias[r]; acc[r]=v>0.f?v:0.f; }
    *(f32x4*)(out+(size_t)node*HH+ob)=acc;
  }
}

extern "C" void kernel_launch(void* const* d_in, const int* in_sizes, int n_in,
                              void* d_out, int out_size, void* d_ws, size_t ws_size,
                              hipStream_t stream)
{
  const float* h     = (const float*)d_in[0];
  const int*   nbr   = (const int*)d_in[1];
  const float* W_ih  = (const float*)d_in[2];
  const float* W_hh  = (const float*)d_in[3];
  const float* b_ih  = (const float*)d_in[4];
  const float* b_hh  = (const float*)d_in[5];
  const float* W_out = (const float*)d_in[6];
  const float* b_out = (const float*)d_in[7];
  unsigned short* Hp = (unsigned short*)d_ws;   // 20000*512*2B = 20.48 MB

  k_hp<<<256, 512, 0, stream>>>(h, W_ih, b_ih, b_hh, Hp);
  k_lstm<<<PAIRS, 512, 0, stream>>>(h, nbr, W_hh, Hp, W_out, b_out, (float*)d_out);
}

// Round 7
// 216.523 us; speedup vs baseline: 3.7525x; 3.7525x over previous
//
#include <hip/hip_runtime.h>

#define NN 20000
#define DD 128
#define HH 128
#define G4 512
#define DEG 32
#define NPB 32     // nodes per pair (2 staggered groups of 16)
#define PAIRS 625  // NN/NPB
#define GRID2 512  // k_lstm grid: exactly 2 blocks/CU resident; extra pairs work-stolen

typedef __attribute__((ext_vector_type(4))) float f32x4;
typedef __attribute__((ext_vector_type(8))) short s16x8;

#ifndef __has_builtin
#define __has_builtin(x) 0
#endif

__device__ int g_cnt;   // next pair index for work stealing; re-armed by k_hp each launch

static __device__ __forceinline__ float fexp2(float x){
#if __has_builtin(__builtin_amdgcn_exp2f)
  return __builtin_amdgcn_exp2f(x);
#else
  return exp2f(x);
#endif
}
static __device__ __forceinline__ float frcp(float x){
#if __has_builtin(__builtin_amdgcn_rcpf)
  return __builtin_amdgcn_rcpf(x);
#else
  return 1.f/x;
#endif
}

// packed f32x2 -> bf16x2 (RNE)
static __device__ __forceinline__ unsigned cvt_pk_bf16(float lo, float hi){
  unsigned r;
  asm("v_cvt_pk_bf16_f32 %0, %1, %2" : "=v"(r) : "v"(lo), "v"(hi));
  return r;
}
static __device__ __forceinline__ s16x8 ld8bf(const float* __restrict__ p){
  f32x4 a = *(const f32x4*)p;
  f32x4 b = *(const f32x4*)(p+4);
  union{unsigned u[4]; s16x8 v;} z;
  z.u[0]=cvt_pk_bf16(a[0],a[1]);
  z.u[1]=cvt_pk_bf16(a[2],a[3]);
  z.u[2]=cvt_pk_bf16(b[0],b[1]);
  z.u[3]=cvt_pk_bf16(b[2],b[3]);
  return z.v;
}
// bf16 packed in u32 -> f32 (bf16 in high 16 bits IS the f32 bit pattern)
static __device__ __forceinline__ float lo16f(unsigned u){
  union{unsigned x; float f;} v; v.x = u << 16; return v.f;
}
static __device__ __forceinline__ float hi16f(unsigned u){
  union{unsigned x; float f;} v; v.x = u & 0xffff0000u; return v.f;
}
#define NLOG2E -1.44269504f
#define TLOG2E  2.88539008f

// ---------------- Phase 1: Hp = h @ W_ih^T + b_ih + b_hh, bf16 ----------------
// PERMUTED layout: Hp element (n, gatecol=128g+16w+4hi+r) stored at
//   n*512 + w*64 + hi*16 + g*4 + r
// so in k_lstm each lane's 16 gate-values are one contiguous 32B chunk.
__global__ __launch_bounds__(512,2) void k_hp(
    const float* __restrict__ h, const float* __restrict__ W_ih,
    const float* __restrict__ b_ih, const float* __restrict__ b_hh,
    unsigned short* __restrict__ Hp)
{
  if(blockIdx.x==0 && threadIdx.x==0) g_cnt = GRID2;  // arm the k_lstm work-steal counter
  const int tid=threadIdx.x, w=tid>>6, lane=tid&63, lo=lane&15, hi=lane>>4;
  s16x8 A[4][4];
#pragma unroll
  for(int g=0;g<4;++g){
    const float* wr=W_ih+(size_t)(128*g+16*w+lo)*DD+8*hi;
#pragma unroll
    for(int c=0;c<4;++c) A[g][c]=ld8bf(wr+32*c);
  }
  f32x4 bb[4];
#pragma unroll
  for(int g=0;g<4;++g){
    const int gcb=128*g+16*w+4*hi;
    bb[g]=*(const f32x4*)(b_ih+gcb) + *(const f32x4*)(b_hh+gcb);
  }
  // grid 256, blocks 0..56 take a second 64-node chunk (313 chunks total)
  const int nchunk = (blockIdx.x < 57) ? 2 : 1;
  for(int cc=0; cc<nchunk; ++cc){
    const int n0 = ((cc? 256+blockIdx.x : blockIdx.x))*64;
    f32x4 acc[4][4];
#pragma unroll
    for(int g=0;g<4;++g)
#pragma unroll
      for(int nt=0;nt<4;++nt) acc[g][nt]=(f32x4)0.f;
#pragma unroll
    for(int c=0;c<4;++c){
      s16x8 B[4];
#pragma unroll
      for(int nt=0;nt<4;++nt){
        int nd=n0+16*nt+lo; if(nd>=NN) nd=NN-1;
        B[nt]=ld8bf(h+(size_t)nd*DD+32*c+8*hi);
      }
#pragma unroll
      for(int g=0;g<4;++g)
#pragma unroll
        for(int nt=0;nt<4;++nt)
          acc[g][nt]=__builtin_amdgcn_mfma_f32_16x16x32_bf16(A[g][c],B[nt],acc[g][nt],0,0,0);
    }
#pragma unroll
    for(int nt=0;nt<4;++nt){
      int nd=n0+16*nt+lo;
      if(nd<NN){
        unsigned short* p = Hp + (size_t)nd*G4 + w*64 + hi*16;
        uint4 q0, q1;
        q0.x=cvt_pk_bf16(acc[0][nt][0]+bb[0][0], acc[0][nt][1]+bb[0][1]);
        q0.y=cvt_pk_bf16(acc[0][nt][2]+bb[0][2], acc[0][nt][3]+bb[0][3]);
        q0.z=cvt_pk_bf16(acc[1][nt][0]+bb[1][0], acc[1][nt][1]+bb[1][1]);
        q0.w=cvt_pk_bf16(acc[1][nt][2]+bb[1][2], acc[1][nt][3]+bb[1][3]);
        q1.x=cvt_pk_bf16(acc[2][nt][0]+bb[2][0], acc[2][nt][1]+bb[2][1]);
        q1.y=cvt_pk_bf16(acc[2][nt][2]+bb[2][2], acc[2][nt][3]+bb[2][3]);
        q1.z=cvt_pk_bf16(acc[3][nt][0]+bb[3][0], acc[3][nt][1]+bb[3][1]);
        q1.w=cvt_pk_bf16(acc[3][nt][2]+bb[3][2], acc[3][nt][3]+bb[3][3]);
        *(uint4*)p = q0;
        *(uint4*)(p+8) = q1;
      }
    }
  }
}

// unpack one lane's 32B Hp chunk into the 4-gate accumulator init
static __device__ __forceinline__ void unpack_acc(const uint4 q[2], f32x4 acc[4]){
  acc[0][0]=lo16f(q[0].x); acc[0][1]=hi16f(q[0].x); acc[0][2]=lo16f(q[0].y); acc[0][3]=hi16f(q[0].y);
  acc[1][0]=lo16f(q[0].z); acc[1][1]=hi16f(q[0].z); acc[1][2]=lo16f(q[0].w); acc[1][3]=hi16f(q[0].w);
  acc[2][0]=lo16f(q[1].x); acc[2][1]=hi16f(q[1].x); acc[2][2]=lo16f(q[1].y); acc[2][3]=hi16f(q[1].y);
  acc[3][0]=lo16f(q[1].z); acc[3][1]=hi16f(q[1].z); acc[3][2]=lo16f(q[1].w); acc[3][3]=hi16f(q[1].w);
}

// LSTM cell for one group: consumes acc, updates cst, packs h to LDS (swizzled)
static __device__ __forceinline__ void cell_update(const f32x4 acc[4], float cst[4],
                                                   char* wb, int waddr){
  float hv[4];
#pragma unroll
  for(int r=0;r<4;++r){
    float ei=fexp2(acc[0][r]*NLOG2E);
    float ef=fexp2(acc[1][r]*NLOG2E);
    float eg=fexp2(acc[2][r]*TLOG2E);
    float eo=fexp2(acc[3][r]*NLOG2E);
    float itg=(eg-1.f)*frcp((1.f+ei)*(1.f+eg));
    float cc=cst[r]*frcp(1.f+ef)+itg;
    cst[r]=cc;
    float ec=fexp2(cc*TLOG2E);
    hv[r]=(ec-1.f)*frcp((1.f+eo)*(1.f+ec));
  }
  uint2 pk;
  pk.x=cvt_pk_bf16(hv[0],hv[1]);
  pk.y=cvt_pk_bf16(hv[2],hv[3]);
  *(uint2*)(wb + waddr) = pk;
}

// ---------------- Phase 2: LSTM scan, staggered pipeline, work-stealing, t-unrolled x2 -----
// Grid = 512 (2 blocks/CU). The t-loop is unrolled by 2 with statically renamed gather
// double-buffers (qAx/qAy, qBx/qBy): a gather issued in interval i is first TOUCHED in
// interval i+2 (no register copies), so its s_waitcnt vmcnt lands a full interval
// (~3900 cy) after issue -- the L2/HBM gather tail (~450-900 cy) is fully hidden.
// (Round 5's qA0<-qA1 copy was a same-interval USE: every interval ended vmcnt-stalled.)
__global__ __launch_bounds__(512,2) void k_lstm(
    const float* __restrict__ h, const int* __restrict__ nbr,
    const float* __restrict__ W_hh, const unsigned short* __restrict__ Hp,
    const float* __restrict__ W_out, const float* __restrict__ b_out,
    float* __restrict__ out)
{
  __shared__ unsigned short hpA[16*HH];      // 4 KB
  __shared__ unsigned short hpB[16*HH];      // 4 KB
  __shared__ int nlds[DEG*NPB];              // transposed: nlds[t][node] = node_idx*G4, 4 KB
  __shared__ int spair;
  const int tid=threadIdx.x, w=tid>>6, lane=tid&63, lo=lane&15, hi=lane>>4;
  const int swz=(lo&7)<<4;
  const int woff=w*64+hi*16;                 // lane's Hp chunk offset (shorts)
  const int raddr0=(lo*256 + 16*hi) ^ swz;   // base for swizzled ds_read (c term added)
  const int waddr=((lo*256 + 32*w + 8*hi) ^ swz);

  s16x8 A[4][4];                             // W_hh fragments in registers, pair-invariant
#pragma unroll
  for(int g=0;g<4;++g){
    const float* wr=W_hh+(size_t)(128*g+16*w+lo)*HH+8*hi;
#pragma unroll
    for(int c=0;c<4;++c) A[g][c]=ld8bf(wr+32*c);
  }

  int pair = blockIdx.x;
  for(;;){
    const int n0 = pair*NPB;
    {
      unsigned* za=(unsigned*)&hpA[0];
      unsigned* zb=(unsigned*)&hpB[0];
      za[tid]=0u; za[tid+512]=0u;            // zero hpA (h0 = 0)
      zb[tid]=0u; zb[tid+512]=0u;            // zero hpB
#pragma unroll
      for(int i=0;i<2;++i){                  // stage neighbor offsets transposed, pre-scaled
        int idx=tid+512*i;
        nlds[(idx&31)*NPB + (idx>>5)] = nbr[n0*DEG + idx]*G4;
      }
    }
    __syncthreads();

    float cstA[4]={0.f,0.f,0.f,0.f}, cstB[4]={0.f,0.f,0.f,0.f};
    // accB(-1)=0 makes the first cellB produce h=0, c=0: exactly h_B(-1).
    f32x4 accA[4], accB[4];
#pragma unroll
    for(int g=0;g<4;++g) accB[g]=(f32x4)0.f;

    // gather double-buffers (statically renamed, no copies)
    uint4 qAx[2], qAy[2], qBx[2], qBy[2];
    {
      const unsigned short* ga=Hp+(size_t)nlds[lo]+woff;
      const unsigned short* gb=Hp+(size_t)nlds[16+lo]+woff;
      qAx[0]=*(const uint4*)ga; qAx[1]=*(const uint4*)(ga+8);
      qBx[0]=*(const uint4*)gb; qBx[1]=*(const uint4*)(gb+8);
    }

#define GATHER(dst, toff) { \
      const unsigned short* gp_=Hp+(size_t)nlds[(toff)*NPB+lo##_SEL]+woff; \
      dst[0]=*(const uint4*)gp_; dst[1]=*(const uint4*)(gp_+8); }

#define INTERVAL_P(QUSE, QLOAD, TLOAD) { \
      { const unsigned short* gp_=Hp+(size_t)nlds[(TLOAD)*NPB+lo]+woff; \
        QLOAD[0]=*(const uint4*)gp_; QLOAD[1]=*(const uint4*)(gp_+8); } \
      s16x8 Ba[4]; \
      const char* ra=(const char*)&hpA[0]; \
      _Pragma("unroll") \
      for(int c=0;c<4;++c) Ba[c]=*(const s16x8*)(ra + (((lo*256 + 64*c + 16*hi)) ^ swz)); \
      cell_update(accB, cstB, (char*)&hpB[0], waddr); \
      unpack_acc(QUSE, accA); \
      _Pragma("unroll") \
      for(int c=0;c<4;++c) \
        _Pragma("unroll") \
        for(int g=0;g<4;++g) \
          accA[g]=__builtin_amdgcn_mfma_f32_16x16x32_bf16(A[g][c],Ba[c],accA[g],0,0,0); \
      asm volatile("s_waitcnt lgkmcnt(0)\n\ts_barrier" ::: "memory"); }

#define INTERVAL_Q(QUSE, QLOAD, TLOAD) { \
      { const unsigned short* gp_=Hp+(size_t)nlds[(TLOAD)*NPB+16+lo]+woff; \
        QLOAD[0]=*(const uint4*)gp_; QLOAD[1]=*(const uint4*)(gp_+8); } \
      s16x8 Bb[4]; \
      const char* rb=(const char*)&hpB[0]; \
      _Pragma("unroll") \
      for(int c=0;c<4;++c) Bb[c]=*(const s16x8*)(rb + (((lo*256 + 64*c + 16*hi)) ^ swz)); \
      cell_update(accA, cstA, (char*)&hpA[0], waddr); \
      unpack_acc(QUSE, accB); \
      _Pragma("unroll") \
      for(int c=0;c<4;++c) \
        _Pragma("unroll") \
        for(int g=0;g<4;++g) \
          accB[g]=__builtin_amdgcn_mfma_f32_16x16x32_bf16(A[g][c],Bb[c],accB[g],0,0,0); \
      asm volatile("s_waitcnt lgkmcnt(0)\n\ts_barrier" ::: "memory"); }

    for(int k=0;k<DEG/2;++k){
      const int t0=2*k, t1=2*k+1;
      const int t2 = (t1+1<DEG)? t1+1 : t1;  // clamp: last dummy load re-reads t=31
      // t even: use x-buffers, load y-buffers (for t1)
      INTERVAL_P(qAx, qAy, t1)
      INTERVAL_Q(qBx, qBy, t1)
      // t odd: use y-buffers, load x-buffers (for t2)
      INTERVAL_P(qAy, qAx, t2)
      INTERVAL_Q(qBy, qBx, t2)
      (void)t0;
    }
#undef INTERVAL_P
#undef INTERVAL_Q
#undef GATHER

    // drain: cell for group B at t=31 -> hpB holds h_B(31)
    cell_update(accB, cstB, (char*)&hpB[0], waddr);
    asm volatile("s_waitcnt lgkmcnt(0)\n\ts_barrier" ::: "memory");

    // ---- fused output projection: out = relu([h, agg] @ W_out^T + b_out) ----
    s16x8 AO[8];
    {
      const float* wr=W_out+(size_t)(16*w+lo)*256+8*hi;
#pragma unroll
      for(int c=0;c<8;++c) AO[c]=ld8bf(wr+32*c);
    }
    const int ob=16*w+4*hi;
    f32x4 bias=*(const f32x4*)(b_out+ob);
#pragma unroll
    for(int nt=0;nt<2;++nt){
      const int node=n0+nt*16+lo;
      s16x8 BB[8];
      const float* hr=h+(size_t)node*DD+8*hi;
#pragma unroll
      for(int c=0;c<4;++c) BB[c]=ld8bf(hr+32*c);
      const char* rb=(const char*)(nt? &hpB[0] : &hpA[0]);
#pragma unroll
      for(int c=0;c<4;++c)
        BB[4+c]=*(const s16x8*)(rb + (((lo*256 + 64*c + 16*hi)) ^ swz));
      f32x4 acc=(f32x4)0.f;
#pragma unroll
      for(int c=0;c<8;++c) acc=__builtin_amdgcn_mfma_f32_16x16x32_bf16(AO[c],BB[c],acc,0,0,0);
#pragma unroll
      for(int r=0;r<4;++r){ float v=acc[r]+bias[r]; acc[r]=v>0.f?v:0.f; }
      *(f32x4*)(out+(size_t)node*HH+ob)=acc;
    }

    // ---- steal the next pair; barrier also protects LDS reuse across pairs ----
    if(tid==0) spair = atomicAdd(&g_cnt, 1);
    __syncthreads();
    pair = spair;
    if(pair >= PAIRS) break;
  }
  (void)raddr0;
}

extern "C" void kernel_launch(void* const* d_in, const int* in_sizes, int n_in,
                              void* d_out, int out_size, void* d_ws, size_t ws_size,
                              hipStream_t stream)
{
  const float* h     = (const float*)d_in[0];
  const int*   nbr   = (const int*)d_in[1];
  const float* W_ih  = (const float*)d_in[2];
  const float* W_hh  = (const float*)d_in[3];
  const float* b_ih  = (const float*)d_in[4];
  const float* b_hh  = (const float*)d_in[5];
  const float* W_out = (const float*)d_in[6];
  const float* b_out = (const float*)d_in[7];
  unsigned short* Hp = (unsigned short*)d_ws;   // 20000*512*2B = 20.48 MB

  k_hp<<<256, 512, 0, stream>>>(h, W_ih, b_ih, b_hh, Hp);
  k_lstm<<<GRID2, 512, 0, stream>>>(h, nbr, W_hh, Hp, W_out, b_out, (float*)d_out);
}